// Round 6
// baseline (228.531 us; speedup 1.0000x reference)
//
#include <hip/hip_runtime.h>
#include <math.h>

#define EPS 1e-12f
constexpr int N_ROWS = 262144;
constexpr int KCODES = 1024;
constexpr int DIM    = 64;
constexpr int CHUNK_SH = 4096;      // shorts per 32-code chunk (hi+lo)
constexpr int TIE_THR = 15;         // flag if top-2 gap <= 15 granules (granule = 32 ulp)

typedef __attribute__((ext_vector_type(8)))  short  short8;
typedef __attribute__((ext_vector_type(16))) float  float16;

__device__ inline unsigned short f2bf(float f) {
    unsigned int u = __float_as_uint(f);
    u = u + 0x7fff + ((u >> 16) & 1);           // RNE
    return (unsigned short)(u >> 16);
}
__device__ inline float bf2f(unsigned short s) {
    return __uint_as_float(((unsigned int)s) << 16);
}

// ---------- K1: normalize codebook -> cc, cnT (transposed), bf16 hi/lo frags ----------
// Frag layout (B-operand, 32x32x16): lane l holds B[k=16s+8*(l>>5)+j][n=32*g+(l&31)]
// ushort idx = ((g*4+s)*2+p)*512 + lane*8 + j   (p: 0=hi,1=lo; g = code>>5)
__global__ __launch_bounds__(64)
void vq_prep(const float* __restrict__ cb, float* __restrict__ cnT,
             float* __restrict__ cc, unsigned short* __restrict__ frag,
             float* __restrict__ dloss) {
    int n = blockIdx.x;      // code
    int d = threadIdx.x;     // dim
    float v = cb[n * DIM + d];
    float s = v * v;
    #pragma unroll
    for (int off = 32; off; off >>= 1) s += __shfl_xor(s, off, 64);
    float vn = v / fmaxf(sqrtf(s), EPS);
    cnT[d * KCODES + n] = vn;                       // transposed for recheck
    float s2 = vn * vn;
    #pragma unroll
    for (int off = 32; off; off >>= 1) s2 += __shfl_xor(s2, off, 64);
    if (d == 0) cc[n] = s2;
    unsigned short hi = f2bf(vn);
    unsigned short lo = f2bf(vn - bf2f(hi));
    int g = n >> 5;
    int lane = (n & 31) + 32 * ((d >> 3) & 1);
    int si = d >> 4, j = d & 7;
    size_t base = (size_t)((g * 4 + si) * 2) * 512 + lane * 8 + j;
    frag[base]       = hi;
    frag[base + 512] = lo;
    if (n == 0 && d == 0) *dloss = 0.f;
}

// ---------- K2: MFMA distances + packed-key argmin + epilogue + inline recheck ----------
__global__ __launch_bounds__(256, 2)
void vq_mfma(const float* __restrict__ x, const unsigned short* __restrict__ frag,
             const float* __restrict__ cb, const float* __restrict__ cnT,
             const float* __restrict__ cc, float* __restrict__ out_q,
             float* __restrict__ out_idx, float* __restrict__ partial,
             float* __restrict__ dloss) {
    __shared__ unsigned short Blds[2][CHUNK_SH];   // 16 KB double buffer (32 codes)
    __shared__ int   ridx[128];
    __shared__ int   blist[128];
    __shared__ int   bcnt;
    __shared__ float redl[4];

    const int tid = threadIdx.x;
    const int w = tid >> 6, l = tid & 63;
    const int lc = l & 31, h = l >> 5;
    const int row0 = blockIdx.x * 128;             // 128 rows per block (32/wave)

    if (tid == 0) bcnt = 0;

    // --- A: one row-tile per wave, rows = row0 + w*32 + lc ---
    short8 ahi[4], alo[4];
    {
        int row = row0 + w * 32 + lc;
        float xv[4][8]; float ss = 0.f;
        #pragma unroll
        for (int s = 0; s < 4; ++s) {
            const float* p = x + (size_t)row * DIM + s * 16 + h * 8;
            float4 a = *(const float4*)p;
            float4 b = *(const float4*)(p + 4);
            xv[s][0]=a.x; xv[s][1]=a.y; xv[s][2]=a.z; xv[s][3]=a.w;
            xv[s][4]=b.x; xv[s][5]=b.y; xv[s][6]=b.z; xv[s][7]=b.w;
            ss += a.x*a.x + a.y*a.y + a.z*a.z + a.w*a.w
                + b.x*b.x + b.y*b.y + b.z*b.z + b.w*b.w;
        }
        ss += __shfl_xor(ss, 32, 64);
        float inv = 1.0f / fmaxf(sqrtf(ss), EPS);
        #pragma unroll
        for (int s = 0; s < 4; ++s)
            #pragma unroll
            for (int j = 0; j < 8; ++j) {
                float v = xv[s][j] * inv;
                unsigned short hb = f2bf(v);
                unsigned short lb = f2bf(v - bf2f(hb));
                ahi[s][j] = (short)hb;
                alo[s][j] = (short)lb;
            }
    }

    int m1[16], m2[16];
    #pragma unroll
    for (int r = 0; r < 16; ++r) { m1[r] = 0; m2[r] = 0; }

    // stage chunk 0 (32 codes = 8 KB; 256 threads x 2 x 16B)
    {
        const unsigned short* g = frag + (w * 2) * 512 + l * 8;
        #pragma unroll
        for (int q = 0; q < 2; ++q)
            __builtin_amdgcn_global_load_lds(
                (const __attribute__((address_space(1))) unsigned int*)(g + q * 512),
                (__attribute__((address_space(3))) unsigned int*)&Blds[0][(w * 2 + q) * 512],
                16, 0, 0);
    }

    for (int c = 0; c < 32; ++c) {
        __syncthreads();                     // DMA for buf[c&1] landed a full chunk ago
        if (c < 31) {                        // prefetch next chunk into the other buffer
            const unsigned short* g = frag + (size_t)(c + 1) * CHUNK_SH + (w * 2) * 512 + l * 8;
            #pragma unroll
            for (int q = 0; q < 2; ++q)
                __builtin_amdgcn_global_load_lds(
                    (const __attribute__((address_space(1))) unsigned int*)(g + q * 512),
                    (__attribute__((address_space(3))) unsigned int*)&Blds[(c + 1) & 1][(w * 2 + q) * 512],
                    16, 0, 0);
        }
        const unsigned short* B = Blds[c & 1];
        short8 bhi[4], blo[4];
        #pragma unroll
        for (int s = 0; s < 4; ++s) {
            bhi[s] = *((const short8*)&B[(s * 2    ) * 512] + l);
            blo[s] = *((const short8*)&B[(s * 2 + 1) * 512] + l);
        }
        // 5-bit tie-break key: ct = code>>5 = c (key-ties always flagged -> rechecked)
        float16 acc;
        #pragma unroll
        for (int r = 0; r < 16; ++r) acc[r] = 2.0f;   // bias: acc = 2 + dot > 0
        #pragma unroll
        for (int s = 0; s < 4; ++s) {
            acc = __builtin_amdgcn_mfma_f32_32x32x16_bf16(ahi[s], bhi[s], acc, 0, 0, 0);
            acc = __builtin_amdgcn_mfma_f32_32x32x16_bf16(alo[s], bhi[s], acc, 0, 0, 0);
            acc = __builtin_amdgcn_mfma_f32_32x32x16_bf16(ahi[s], blo[s], acc, 0, 0, 0);
        }
        #pragma unroll
        for (int r = 0; r < 16; ++r) {
            int k = (__float_as_int(acc[r]) & (int)0xFFFFFFE0) | c;
            // m2 = median(m1, m2, k) == new second-best given invariant m2 <= m1
            int nm2;
            asm("v_med3_i32 %0, %1, %2, %3"
                : "=v"(nm2) : "v"(m1[r]), "v"(m2[r]), "v"(k));
            m2[r] = nm2;
            m1[r] = max(m1[r], k);
        }
    }

    // --- cross-lane merge over the 32 code-lanes (packed keys) ---
    #pragma unroll
    for (int r = 0; r < 16; ++r) {
        int a = m1[r], b = m2[r];
        #pragma unroll
        for (int off = 1; off < 32; off <<= 1) {
            int oa = __shfl_xor(a, off, 64);
            int ob = __shfl_xor(b, off, 64);
            int nb = max(max(b, ob), min(a, oa));
            a = max(a, oa); b = nb;
        }
        // winner lane: lanes with m1 == a; code = ct*32 + lane. Key-ties flagged.
        unsigned long long ball = __ballot(m1[r] == a);
        unsigned m32 = h ? (unsigned)(ball >> 32) : (unsigned)ball;
        if (lc == 0) {
            int rowl = w * 32 + (r & 3) + 8 * (r >> 2) + 4 * h;
            int wlc = 31 - __builtin_clz(m32);
            ridx[rowl] = (a & 31) * 32 + wlc;
            if (((a >> 5) - (b >> 5)) <= TIE_THR) {   // near-tie under truncation
                int p = atomicAdd(&bcnt, 1);
                if (p < 128) blist[p] = rowl;
            }
        }
    }
    __syncthreads();

    if (tid < 128) out_idx[row0 + tid] = (float)ridx[tid];

    // --- gather + out_q + loss partial (x re-read is L3-hot) ---
    float lsum = 0.f;
    const float4* cb4 = (const float4*)cb;
    const float4* x4  = (const float4*)x;
    float4*       o4  = (float4*)out_q;
    #pragma unroll
    for (int i = 0; i < 8; ++i) {
        int f = tid + 256 * i;            // 0..2047
        int r = f >> 4, c4 = f & 15;
        float4 q  = cb4[ridx[r] * 16 + c4];
        float4 xr = x4[(size_t)row0 * 16 + f];
        o4[(size_t)row0 * 16 + f] = q;
        float dx = q.x - xr.x, dy = q.y - xr.y, dz = q.z - xr.z, dw = q.w - xr.w;
        lsum += dx * dx + dy * dy + dz * dz + dw * dw;
    }
    #pragma unroll
    for (int off = 32; off; off >>= 1) lsum += __shfl_xor(lsum, off, 64);
    if (l == 0) redl[w] = lsum;
    __syncthreads();    // also orders the gather out_q writes before recheck patches
    if (tid == 0) partial[blockIdx.x] = redl[0] + redl[1] + redl[2] + redl[3];

    // --- inline exact fp32 recheck of this block's flagged rows (rare: ~0.23/block) ---
    int nfl = bcnt; if (nfl > 128) nfl = 128;
    for (int e = w; e < nfl; e += 4) {          // one wave per flagged row
        int rowl = blist[e];
        int row  = row0 + rowl;
        float xl = x[(size_t)row * DIM + l];
        float ss = xl * xl;
        #pragma unroll
        for (int off = 32; off; off >>= 1) ss += __shfl_xor(ss, off, 64);
        float inv = 1.0f / fmaxf(sqrtf(ss), EPS);
        float dot[16];
        #pragma unroll
        for (int kk = 0; kk < 16; ++kk) dot[kk] = 0.f;
        for (int d = 0; d < 64; ++d) {
            float xd = __shfl(xl, d, 64);
            #pragma unroll
            for (int kk = 0; kk < 16; ++kk)      // lanes consecutive -> coalesced
                dot[kk] = fmaf(xd, cnT[d * KCODES + l + 64 * kk], dot[kk]);
        }
        float best = INFINITY; int bix = 0x7fffffff;
        #pragma unroll
        for (int kk = 0; kk < 16; ++kk) {
            int k = l + 64 * kk;                 // ascending per lane
            float dist = cc[k] - 2.0f * (inv * dot[kk]);
            if (dist < best) { best = dist; bix = k; }
        }
        #pragma unroll
        for (int off = 1; off < 64; off <<= 1) {
            float ob = __shfl_xor(best, off, 64);
            int   oi = __shfl_xor(bix,  off, 64);
            if (ob < best || (ob == best && oi < bix)) { best = ob; bix = oi; }
        }
        int oldi = ridx[rowl];
        if (bix != oldi) {
            float qn = cb[(size_t)bix  * DIM + l];
            float qo = cb[(size_t)oldi * DIM + l];
            float an = qn - xl, ao = qo - xl;
            float dl = an * an - ao * ao;
            #pragma unroll
            for (int off = 32; off; off >>= 1) dl += __shfl_xor(dl, off, 64);
            out_q[(size_t)row * DIM + l] = qn;
            if (l == 0) { out_idx[row] = (float)bix; atomicAdd(dloss, dl); }
        }
    }
}

// ---------- K3: reduce partials (+delta) -> both losses ----------
__global__ __launch_bounds__(256)
void vq_final(const float* __restrict__ partial, const float* __restrict__ dloss,
              float* __restrict__ out_loss) {
    float s = 0.f;
    for (int i = threadIdx.x; i < 2048; i += 256) s += partial[i];
    #pragma unroll
    for (int off = 32; off; off >>= 1) s += __shfl_xor(s, off, 64);
    __shared__ float red[4];
    if ((threadIdx.x & 63) == 0) red[threadIdx.x >> 6] = s;
    __syncthreads();
    if (threadIdx.x == 0) {
        float t = red[0] + red[1] + red[2] + red[3] + *dloss;
        float m = t / (float)((size_t)N_ROWS * DIM);
        out_loss[0] = m;   // codebook_loss
        out_loss[1] = m;   // commitment_loss (same forward value)
    }
}

extern "C" void kernel_launch(void* const* d_in, const int* in_sizes, int n_in,
                              void* d_out, int out_size, void* d_ws, size_t ws_size,
                              hipStream_t stream) {
    const float* x  = (const float*)d_in[0];   // [262144, 64]
    const float* cb = (const float*)d_in[1];   // [1024, 64]
    float* out = (float*)d_out;
    float* out_q    = out;                               // [N*D]
    float* out_loss = out + (size_t)N_ROWS * DIM;        // [2]
    float* out_idx  = out_loss + 2;                      // [N]

    char* ws = (char*)d_ws;
    float*          cnT     = (float*)(ws);                    // 262144 B
    float*          cc      = (float*)(ws + 262144);           //   4096 B
    unsigned short* frag    = (unsigned short*)(ws + 266240);  // 262144 B
    float*          dloss   = (float*)(ws + 528388);           //      4 B
    float*          partial = (float*)(ws + 790544);           //   8192 B (2048 blocks)

    vq_prep <<<KCODES, 64, 0, stream>>>(cb, cnT, cc, frag, dloss);
    vq_mfma <<<N_ROWS / 128, 256, 0, stream>>>(x, frag, cb, cnT, cc,
                                               out_q, out_idx, partial, dloss);
    vq_final<<<1, 256, 0, stream>>>(partial, dloss, out_loss);
}